// Round 2
// baseline (66.116 us; speedup 1.0000x reference)
//
#include <hip/hip_runtime.h>
#include <hip/hip_bf16.h>

// Shift3x3: out[b,c,i,j] = x[b,c, i+di(c%5), j+dj(c%5)], zero at borders.
//   c%5==0: (di,dj)=(-1, 0)   c%5==1: (0,-1)   c%5==2: (0,0)
//   c%5==3: (di,dj)=( 0,+1)   c%5==4: (+1, 0)
// Shapes: B=32, C=384, H=56, W=56, float32 in/out. Pure memory-bound.
//
// Each thread produces 8 consecutive floats (32B, two aligned float4).
// Horizontal shifts (mod 1/3) use 2 aligned float4 loads + 1 boundary scalar
// and shift in-register, instead of 8 scalar loads.

#define SH_W 56
#define SH_H 56
#define SH_C 384
#define SH_W8 7             // W/8 chunks per row
#define SH_PLANE8 392       // H * W8
#define SH_PLANE 3136       // H * W

__global__ void Shift3x3_kernel(const float* __restrict__ x,
                                float* __restrict__ out, int n8) {
    int idx = blockIdx.x * blockDim.x + threadIdx.x;
    const int stride = gridDim.x * blockDim.x;
    for (; idx < n8; idx += stride) {
        int plane = idx / SH_PLANE8;          // b*C + c
        int rem   = idx - plane * SH_PLANE8;  // chunk within plane
        int i     = rem / SH_W8;              // row
        int j     = (rem - i * SH_W8) * 8;    // col (0,8,...,48)
        int c     = plane % SH_C;
        int mod   = c % 5;
        int base  = plane * SH_PLANE + i * SH_W + j;
        const float* p = x + base;

        float4 v0, v1;
        if (mod == 2) {
            v0 = *reinterpret_cast<const float4*>(p);
            v1 = *reinterpret_cast<const float4*>(p + 4);
        } else if (mod == 0) {
            if (i == 0) {
                v0 = make_float4(0.f, 0.f, 0.f, 0.f);
                v1 = v0;
            } else {
                v0 = *reinterpret_cast<const float4*>(p - SH_W);
                v1 = *reinterpret_cast<const float4*>(p - SH_W + 4);
            }
        } else if (mod == 4) {
            if (i == SH_H - 1) {
                v0 = make_float4(0.f, 0.f, 0.f, 0.f);
                v1 = v0;
            } else {
                v0 = *reinterpret_cast<const float4*>(p + SH_W);
                v1 = *reinterpret_cast<const float4*>(p + SH_W + 4);
            }
        } else if (mod == 1) {
            // need x[j-1 .. j+6]
            float4 a = *reinterpret_cast<const float4*>(p);      // j..j+3
            float4 b = *reinterpret_cast<const float4*>(p + 4);  // j+4..j+7
            float m1 = (j == 0) ? 0.f : p[-1];
            v0 = make_float4(m1, a.x, a.y, a.z);
            v1 = make_float4(a.w, b.x, b.y, b.z);
        } else {  // mod == 3
            // need x[j+1 .. j+8]
            float4 a = *reinterpret_cast<const float4*>(p);
            float4 b = *reinterpret_cast<const float4*>(p + 4);
            float p8 = (j == SH_W - 8) ? 0.f : p[8];
            v0 = make_float4(a.y, a.z, a.w, b.x);
            v1 = make_float4(b.y, b.z, b.w, p8);
        }
        *reinterpret_cast<float4*>(out + base)     = v0;
        *reinterpret_cast<float4*>(out + base + 4) = v1;
    }
}

extern "C" void kernel_launch(void* const* d_in, const int* in_sizes, int n_in,
                              void* d_out, int out_size, void* d_ws, size_t ws_size,
                              hipStream_t stream) {
    const float* x = (const float*)d_in[0];
    float* out = (float*)d_out;
    int n8 = out_size / 8;  // 4,816,896 chunks of 8 floats
    int block = 256;
    int grid = (n8 + block - 1) / block;
    if (grid > 2048) grid = 2048;
    Shift3x3_kernel<<<grid, block, 0, stream>>>(x, out, n8);
}

// Round 3
// 54.905 us; speedup vs baseline: 1.2042x; 1.2042x over previous
//
#include <hip/hip_runtime.h>
#include <hip/hip_bf16.h>

// Shift3x3: out[b,c,i,j] = x[b,c, i+di(c%5), j+dj(c%5)], zero at borders.
//   c%5==0: (di,dj)=(-1, 0)   c%5==1: (0,-1)   c%5==2: (0,0)
//   c%5==3: (di,dj)=( 0,+1)   c%5==4: (+1, 0)
// Shapes: B=32, C=384, H=56, W=56, float32 in/out. Pure memory-bound.
//
// 16B (one float4) per thread: per-instruction lane addresses are fully
// contiguous (1KB/wave-instruction). Horizontal shifts (mod 1/3) reuse the
// aligned float4 and get the neighbor element via __shfl from lane +/-1
// (neighbor float4 lives there); wave-edge lanes take one exec-masked
// scalar load; row borders are zero-filled.

#define SH_W 56
#define SH_H 56
#define SH_C 384
#define SH_W4 14            // W/4 float4 per row
#define SH_PLANE4 784       // H * W4
#define SH_PLANE 3136       // H * W

__global__ void Shift3x3_kernel(const float* __restrict__ x,
                                float* __restrict__ out, int n4) {
    int idx = blockIdx.x * blockDim.x + threadIdx.x;
    const int stride = gridDim.x * blockDim.x;
    const int lane = threadIdx.x & 63;
    for (; idx < n4; idx += stride) {
        int plane = idx / SH_PLANE4;          // b*C + c
        int rem   = idx - plane * SH_PLANE4;  // float4 within plane
        int i     = rem / SH_W4;              // row
        int j     = (rem - i * SH_W4) * 4;    // col (0,4,...,52)
        int c     = plane % SH_C;
        int mod   = c % 5;
        int base  = plane * SH_PLANE + i * SH_W + j;
        const float* p = x + base;

        float4 v;
        if (mod == 0) {
            v = (i == 0) ? make_float4(0.f, 0.f, 0.f, 0.f)
                         : *reinterpret_cast<const float4*>(p - SH_W);
        } else if (mod == 4) {
            v = (i == SH_H - 1) ? make_float4(0.f, 0.f, 0.f, 0.f)
                                : *reinterpret_cast<const float4*>(p + SH_W);
        } else {
            float4 a = *reinterpret_cast<const float4*>(p);  // x[j..j+3]
            if (mod == 2) {
                v = a;
            } else if (mod == 1) {
                // need x[j-1] = prev float4's .w = lane-1's a.w
                float y = __shfl_up(a.w, 1);
                if (lane == 0 && j != 0) y = p[-1];
                if (j == 0) y = 0.f;
                v = make_float4(y, a.x, a.y, a.z);
            } else {  // mod == 3
                // need x[j+4] = next float4's .x = lane+1's a.x
                float y = __shfl_down(a.x, 1);
                if (lane == 63 && j != SH_W - 4) y = p[4];
                if (j == SH_W - 4) y = 0.f;
                v = make_float4(a.y, a.z, a.w, y);
            }
        }
        *reinterpret_cast<float4*>(out + base) = v;
    }
}

extern "C" void kernel_launch(void* const* d_in, const int* in_sizes, int n_in,
                              void* d_out, int out_size, void* d_ws, size_t ws_size,
                              hipStream_t stream) {
    const float* x = (const float*)d_in[0];
    float* out = (float*)d_out;
    int n4 = out_size / 4;  // 9,633,792 float4 stores
    int block = 256;
    int grid = (n4 + block - 1) / block;
    if (grid > 2048) grid = 2048;
    Shift3x3_kernel<<<grid, block, 0, stream>>>(x, out, n4);
}

// Round 4
// 49.927 us; speedup vs baseline: 1.3242x; 1.0997x over previous
//
#include <hip/hip_runtime.h>
#include <hip/hip_bf16.h>

// Shift3x3: out[b,c,i,j] = x[b,c, i+di(c%5), j+dj(c%5)], zero at borders.
//   c%5==0: (di,dj)=(-1, 0)   c%5==1: (0,-1)   c%5==2: (0,0)
//   c%5==3: (di,dj)=( 0,+1)   c%5==4: (+1, 0)
// Shapes: B=32, C=384, H=56, W=56, float32 in/out. Pure memory-bound.
//
// 16B (one float4) per thread, fully-coalesced lane addressing.
// Horizontal shifts (mod 1/3) get the neighbor element via __shfl.
// Output stores are NON-TEMPORAL: output is never re-read, and letting it
// allocate in L2/L3 evicts the (L3-resident, 147 MiB) input between graph
// replays — nt stores keep the input fully cached, cutting HBM reads to ~0.

#define SH_W 56
#define SH_H 56
#define SH_C 384
#define SH_W4 14            // W/4 float4 per row
#define SH_PLANE4 784       // H * W4
#define SH_PLANE 3136       // H * W

typedef float f32x4 __attribute__((ext_vector_type(4)));

__global__ void Shift3x3_kernel(const float* __restrict__ x,
                                float* __restrict__ out, int n4) {
    int idx = blockIdx.x * blockDim.x + threadIdx.x;
    const int stride = gridDim.x * blockDim.x;
    const int lane = threadIdx.x & 63;
    for (; idx < n4; idx += stride) {
        int plane = idx / SH_PLANE4;          // b*C + c
        int rem   = idx - plane * SH_PLANE4;  // float4 within plane
        int i     = rem / SH_W4;              // row
        int j     = (rem - i * SH_W4) * 4;    // col (0,4,...,52)
        int c     = plane % SH_C;
        int mod   = c % 5;
        int base  = plane * SH_PLANE + i * SH_W + j;
        const float* p = x + base;

        f32x4 v;
        if (mod == 0) {
            if (i == 0) v = (f32x4){0.f, 0.f, 0.f, 0.f};
            else        v = *reinterpret_cast<const f32x4*>(p - SH_W);
        } else if (mod == 4) {
            if (i == SH_H - 1) v = (f32x4){0.f, 0.f, 0.f, 0.f};
            else               v = *reinterpret_cast<const f32x4*>(p + SH_W);
        } else {
            f32x4 a = *reinterpret_cast<const f32x4*>(p);  // x[j..j+3]
            if (mod == 2) {
                v = a;
            } else if (mod == 1) {
                // need x[j-1] = prev float4's .w = lane-1's a.w
                float y = __shfl_up(a.w, 1);
                if (lane == 0 && j != 0) y = p[-1];
                if (j == 0) y = 0.f;
                v = (f32x4){y, a.x, a.y, a.z};
            } else {  // mod == 3
                // need x[j+4] = next float4's .x = lane+1's a.x
                float y = __shfl_down(a.x, 1);
                if (lane == 63 && j != SH_W - 4) y = p[4];
                if (j == SH_W - 4) y = 0.f;
                v = (f32x4){a.y, a.z, a.w, y};
            }
        }
        __builtin_nontemporal_store(v, reinterpret_cast<f32x4*>(out + base));
    }
}

extern "C" void kernel_launch(void* const* d_in, const int* in_sizes, int n_in,
                              void* d_out, int out_size, void* d_ws, size_t ws_size,
                              hipStream_t stream) {
    const float* x = (const float*)d_in[0];
    float* out = (float*)d_out;
    int n4 = out_size / 4;  // 9,633,792 float4 stores
    int block = 256;
    int grid = (n4 + block - 1) / block;
    if (grid > 2048) grid = 2048;
    Shift3x3_kernel<<<grid, block, 0, stream>>>(x, out, n4);
}